// Round 5
// baseline (172.149 us; speedup 1.0000x reference)
//
#include <hip/hip_runtime.h>

// ODE-RNN encoder: B=2048, T=64, HID=16, adaptive Tsit5 + GRU.
// Round 10: chain-latency trims on the R9 structure (R9 proved we are
// dependent-chain-latency-bound: R2 and R4 both measure ~1650 cy/ODE-iter
// with different issue counts; 2 waves/SIMD would be issue-bound -> worse).
//  (a) activation scale folding: 2*log2(e) pre-multiplied into w1,w2,b1,b2
//      and -log2(e) into r/z gate weights+seeds at load time -> deletes the
//      mul feeding every exp2 on the chain (12/iter).
//  (b) 1/16 mean folded into the error 'scale' constant (0.04/4e-4).
//  (c) fac clamp via v_med3_f32 (__builtin_amdgcn_fmed3f).
// Structure (R9): 32 lanes/sample, 2 samples/wave, 1024 blocks x 64; skewed
// state, col-split dot: 3-DPP gather, 4 pk-FMAs (rows j & j+8), ROR8 B-ship,
// permlane32_swap cross-half pair-sum, row-masked ROR4 re-skew.

#define T_STEPS 64
#define NB 2048
#define N_ODE_STEPS 16

typedef float v2f __attribute__((ext_vector_type(2)));
typedef int v2i __attribute__((ext_vector_type(2)));

__device__ __forceinline__ v2f make2(float a, float b) { v2f r; r.x = a; r.y = b; return r; }

// row_ror:r  => dst lane n gets src lane (n - r) & 15 (within 16-lane row)
#define ROR(x, r) __int_as_float(__builtin_amdgcn_update_dpp( \
    0, __float_as_int(x), 0x120 + (r), 0xF, 0xF, true))

// rotate-by-4 applied ONLY to rows 2,3 (lanes 32-63); rows 0,1 keep x.
#define ROR4_HI(x) __int_as_float(__builtin_amdgcn_update_dpp( \
    __float_as_int(x), __float_as_int(x), 0x124, 0xC, 0xF, false))

__device__ __forceinline__ float rsum16(float v) {
  v += ROR(v, 8);
  v += ROR(v, 4);
  v += ROR(v, 2);
  v += ROR(v, 1);
  return v;  // all 16 lanes hold the row sum (bitwise lane-uniform)
}

// cross-half combine: returns part + part_from(lane^32).
// With both operands equal, v_permlane32_swap returns {own-half, other-half}
// per lane -> their sum is the pair sum at every lane.
__device__ __forceinline__ float xhalf_sum(float part) {
  v2i pr = __builtin_amdgcn_permlane32_swap(
      __float_as_int(part), __float_as_int(part), false, false);
  return __int_as_float(pr[0]) + __int_as_float(pr[1]);
}

struct G2 { v2f a, b; };

// rotations 0..3 of the (skewed) state within each 16-row: 3 DPP, depth 2
__device__ __forceinline__ G2 gather4(float x) {
  float r1 = ROR(x, 1);
  float r2 = ROR(x, 2);
  float r3 = ROR(r2, 1);
  G2 g; g.a = make2(x, r1); g.b = make2(r2, r3); return g;
}

// Full 16-col dot for row j (at every lane), then re-skewed to state layout.
// WA = row j cols {base-0..-3}, WB = row j+8 same cols (base = j-4*hf).
__device__ __forceinline__ float dotG(const v2f (&WA)[2], const v2f (&WB)[2],
                                      const G2& g, float seed) {
  v2f aa = __builtin_elementwise_fma(g.a, WA[0], make2(seed, 0.0f));
  v2f bb = g.a * WB[0];
  aa = __builtin_elementwise_fma(g.b, WA[1], aa);
  bb = __builtin_elementwise_fma(g.b, WB[1], bb);
  float a  = aa.x + aa.y;          // A partial: row j, this lane's 4 cols
  float bs = bb.x + bb.y;          // B partial: row j+8, this lane's 4 cols
  float part = a + ROR(bs, 8);     // row j partial: 8 cols (this half)
  return ROR4_HI(xhalf_sum(part)); // all 16 cols, re-skewed
}

__device__ __forceinline__ float dotAB(const v2f (&WA)[2], const v2f (&WB)[2],
                                       float x, float seed) {
  G2 g = gather4(x);
  return dotG(WA, WB, g, seed);
}

// tanh from a PRE-SCALED argument p = 2*log2(e)*x (scale folded into weights)
__device__ __forceinline__ float tanh_p(float p) {
  float e = __builtin_amdgcn_exp2f(p);
  return fmaf(-2.0f, __builtin_amdgcn_rcpf(e + 1.0f), 1.0f);
}

// sigmoid from a PRE-SCALED argument p = -log2(e)*x
__device__ __forceinline__ float sig_p(float p) {
  float e = __builtin_amdgcn_exp2f(p);
  return __builtin_amdgcn_rcpf(1.0f + e);
}

// unscaled tanh (n-gate: input is a runtime product, can't fold)
__device__ __forceinline__ float fast_tanh(float x) {
  float e = __builtin_amdgcn_exp2f(x * 2.885390081777927f);  // 2*log2(e)
  return fmaf(-2.0f, __builtin_amdgcn_rcpf(e + 1.0f), 1.0f);
}

__device__ __forceinline__ float mlp_f(float u,
    const v2f (&w1a)[2], const v2f (&w1b)[2], float b1s,
    const v2f (&w2a)[2], const v2f (&w2b)[2], float b2s,
    const v2f (&w3a)[2], const v2f (&w3b)[2], float b3s) {
  float h1 = tanh_p(dotAB(w1a, w1b, u, b1s));   // w1/b1 pre-scaled by 2log2e
  float h2 = tanh_p(dotAB(w2a, w2b, h1, b2s));  // w2/b2 pre-scaled by 2log2e
  return dotAB(w3a, w3b, h2, b3s);              // w3/b3 unscaled (k output)
}

__global__
__attribute__((amdgpu_flat_work_group_size(64, 64), amdgpu_waves_per_eu(1, 1)))
void odern_kernel(
    const float* __restrict__ x_seq,
    const float* __restrict__ w1, const float* __restrict__ b1,
    const float* __restrict__ w2, const float* __restrict__ b2,
    const float* __restrict__ w3, const float* __restrict__ b3,
    const float* __restrict__ gru_wih, const float* __restrict__ gru_whh,
    const float* __restrict__ gru_b, const float* __restrict__ gru_bn,
    const float* __restrict__ pred_w, const float* __restrict__ pred_b,
    float* __restrict__ out) {
  const int tid = threadIdx.x;
  const int j = tid & 15;          // lane position within 16-row
  const int row16 = tid >> 4;      // 0..3
  const int smp = row16 & 1;       // sample-in-wave: rows {0,2}=0, {1,3}=1
  const int hf = row16 >> 1;       // half: 0 = cols j..j-7, 1 = cols j-4..j-15
  const int b = blockIdx.x * 2 + smp;
  const int jj = (j + 8) & 15;     // B-dot row
  const int base = (j - 4 * hf) & 15;  // hidden index of this lane's state slot

  const float TS = 2.885390081777927f;    // 2*log2(e)  (tanh input scale)
  const float SS = -1.4426950408889634f;  // -log2(e)   (sigmoid input scale)

  // Per-lane weights: WA[p] = (M[j][c_{2p}], M[j][c_{2p+1}]), c_r = (base-r)&15
  //                   WB[p] = same cols, row jj. w1/w2 & r/z gates pre-scaled.
  v2f w1a[2], w1b[2], w2a[2], w2b[2], w3a[2], w3b[2];
  v2f wha[2], whb[2], wza[2], wzb[2], wna[2], wnb[2];
#pragma unroll
  for (int p = 0; p < 2; ++p) {
    const int ca = (base - 2 * p) & 15;
    const int cb = (base - 2 * p - 1) & 15;
    w1a[p] = make2(w1[j * 16 + ca] * TS,  w1[j * 16 + cb] * TS);
    w1b[p] = make2(w1[jj * 16 + ca] * TS, w1[jj * 16 + cb] * TS);
    w2a[p] = make2(w2[j * 16 + ca] * TS,  w2[j * 16 + cb] * TS);
    w2b[p] = make2(w2[jj * 16 + ca] * TS, w2[jj * 16 + cb] * TS);
    w3a[p] = make2(w3[j * 16 + ca],  w3[j * 16 + cb]);
    w3b[p] = make2(w3[jj * 16 + ca], w3[jj * 16 + cb]);
    wha[p] = make2(gru_whh[j * 16 + ca] * SS,         gru_whh[j * 16 + cb] * SS);
    whb[p] = make2(gru_whh[jj * 16 + ca] * SS,        gru_whh[jj * 16 + cb] * SS);
    wza[p] = make2(gru_whh[(16 + j) * 16 + ca] * SS,  gru_whh[(16 + j) * 16 + cb] * SS);
    wzb[p] = make2(gru_whh[(16 + jj) * 16 + ca] * SS, gru_whh[(16 + jj) * 16 + cb] * SS);
    wna[p] = make2(gru_whh[(32 + j) * 16 + ca],  gru_whh[(32 + j) * 16 + cb]);
    wnb[p] = make2(gru_whh[(32 + jj) * 16 + ca], gru_whh[(32 + jj) * 16 + cb]);
  }
  // Seeds are injected once per output row, via the hf=0 A-chain only.
  const float b1s = hf ? 0.0f : b1[j] * TS;
  const float b2s = hf ? 0.0f : b2[j] * TS;
  const float b3s = hf ? 0.0f : b3[j];
  // r/z gates: only used as dot seeds -> zero at hf=1; pre-scaled by SS.
  const float wih_r0 = hf ? 0.0f : gru_wih[j * 2] * SS;
  const float wih_r1 = hf ? 0.0f : gru_wih[j * 2 + 1] * SS;
  const float wih_z0 = hf ? 0.0f : gru_wih[(16 + j) * 2] * SS;
  const float wih_z1 = hf ? 0.0f : gru_wih[(16 + j) * 2 + 1] * SS;
  const float gb_r = hf ? 0.0f : gru_b[j] * SS;
  const float gb_z = hf ? 0.0f : gru_b[16 + j] * SS;
  const float bns  = hf ? 0.0f : gru_bn[j];
  // n gate input is used ELEMENTWISE (skewed space) -> base-indexed, all lanes.
  const float wih_n0 = gru_wih[(32 + base) * 2];
  const float wih_n1 = gru_wih[(32 + base) * 2 + 1];
  const float gb_n = gru_b[32 + base];
  const float pwv = pred_w[base], pbv = pred_b[0];

  const float* xp = x_seq + (size_t)b * (T_STEPS * 2);

  float hst = 0.0f;
#pragma unroll 1
  for (int t = 0; t < T_STEPS; ++t) {
    const float x0 = xp[2 * t];
    const float x1 = xp[2 * t + 1];

    // ---- adaptive Tsit5 from t=0 to t=1, <=16 iterations, early exit ----
    float y = hst;
    float tt = 0.0f, dt = 1.0f;
    float k1 = mlp_f(y, w1a, w1b, b1s, w2a, w2b, b2s, w3a, w3b, b3s);
#pragma unroll 1
    for (int s = 0; s < N_ODE_STEPS; ++s) {
      // Wave-uniform early exit (2 samples; accept logic is row-uniform).
      if (__all(tt >= 1.0f)) break;

      const float dt_c = fminf(dt, 1.0f - tt);
      const float d = dt_c;

      float s2 = 0.161f * k1;
      float k2 = mlp_f(fmaf(d, s2, y), w1a, w1b, b1s, w2a, w2b, b2s, w3a, w3b, b3s);

      float s3 = fmaf(0.335480655492357f, k2, -0.008480655492356989f * k1);
      float k3 = mlp_f(fmaf(d, s3, y), w1a, w1b, b1s, w2a, w2b, b2s, w3a, w3b, b3s);

      float s4 = fmaf(4.3622954328695815f, k3,
                 fmaf(-6.359448489975075f, k2, 2.8971530571054935f * k1));
      float k4 = mlp_f(fmaf(d, s4, y), w1a, w1b, b1s, w2a, w2b, b2s, w3a, w3b, b3s);

      float s5 = fmaf(-0.09249506636175525f, k4,
                 fmaf(7.4955393428898365f, k3,
                 fmaf(-11.748883564062828f, k2, 5.325864828439257f * k1)));
      float k5 = mlp_f(fmaf(d, s5, y), w1a, w1b, b1s, w2a, w2b, b2s, w3a, w3b, b3s);

      float s6 = fmaf(-0.028269050394068383f, k5,
                 fmaf(-0.071584973281401f, k4,
                 fmaf(8.159367898576159f, k3,
                 fmaf(-12.92096931784711f, k2, 5.86145544294642f * k1))));
      float k6 = mlp_f(fmaf(d, s6, y), w1a, w1b, b1s, w2a, w2b, b2s, w3a, w3b, b3s);

      float sy = fmaf(2.324710524099774f, k6,
                 fmaf(-3.290069515436081f, k5,
                 fmaf(1.379008574103742f, k4,
                 fmaf(0.4798896504144996f, k3,
                 fmaf(0.01f, k2, 0.09646076681806523f * k1)))));
      float y_new = fmaf(d, sy, y);

      float k7 = mlp_f(y_new, w1a, w1b, b1s, w2a, w2b, b2s, w3a, w3b, b3s);

      float se = fmaf(0.015151515151515152f, k7,
                 fmaf(-0.45808210592918697f, k6,
                 fmaf(0.5823571654525552f, k5,
                 fmaf(-0.1447110071732629f, k4,
                 fmaf(0.007880878010261995f, k3,
                 fmaf(-0.0008164344596567469f, k2, -0.001780011052225777f * k1))))));
      float err = d * se;

      // scale4 = 4*(atol + rtol*max) so that rsum16((err/scale4)^2) directly
      // equals mean((err/scale)^2) (the 1/16 is folded in: (1/4)^2 * 16 = 1).
      float scale4 = fmaf(0.04f, fmaxf(fabsf(y), fabsf(y_new)), 0.0004f);
      float r = err * __builtin_amdgcn_rcpf(scale4);
      float err2 = fmaxf(rsum16(r * r), 1e-16f);

      const bool acc = err2 <= 1.0f;
      y = acc ? y_new : y;
      tt = acc ? tt + dt_c : tt;
      k1 = acc ? k7 : k1;   // FSAL: f(y_new) == k7 bitwise, else keep k1

      float fac = 0.9f * __builtin_amdgcn_exp2f(-0.1f * __builtin_amdgcn_logf(err2));
      fac = __builtin_amdgcn_fmed3f(fac, 0.2f, 10.0f);   // clamp in one op
      dt = dt_c * fac;
    }

    // ---- GRU update: one shared gather feeds all 3 dots ----
    float ir  = fmaf(wih_r1, x1, fmaf(wih_r0, x0, gb_r));   // pre-scaled, 0 at hf=1
    float iz  = fmaf(wih_z1, x1, fmaf(wih_z0, x0, gb_z));   // pre-scaled, 0 at hf=1
    float in_ = fmaf(wih_n1, x1, fmaf(wih_n0, x0, gb_n));   // skewed, all lanes
    G2 gy = gather4(y);
    float pre_r = dotG(wha, whb, gy, ir);    // -log2e*(ir + hr)   (skewed)
    float pre_z = dotG(wza, wzb, gy, iz);    // -log2e*(iz + hz)   (skewed)
    float hnb   = dotG(wna, wnb, gy, bns);   // hn + bn            (skewed)
    float rg = sig_p(pre_r);
    float zg = sig_p(pre_z);
    float ng = fast_tanh(fmaf(rg, hnb, in_));
    hst = fmaf(zg, y - ng, ng);
  }

  // ---- final projection: out[b] = h . pred_w + pred_b ----
  float ps = rsum16(hst * pwv);
  if (hf == 0 && j == 0) out[b] = ps + pbv;   // rows 0,1: one writer per sample
}

extern "C" void kernel_launch(void* const* d_in, const int* in_sizes, int n_in,
                              void* d_out, int out_size, void* d_ws, size_t ws_size,
                              hipStream_t stream) {
  (void)in_sizes; (void)n_in; (void)out_size; (void)d_ws; (void)ws_size;
  odern_kernel<<<dim3(NB / 2), dim3(64), 0, stream>>>(
      (const float*)d_in[0],
      (const float*)d_in[1], (const float*)d_in[2],
      (const float*)d_in[3], (const float*)d_in[4],
      (const float*)d_in[5], (const float*)d_in[6],
      (const float*)d_in[7], (const float*)d_in[8],
      (const float*)d_in[9], (const float*)d_in[10],
      (const float*)d_in[11], (const float*)d_in[12],
      (float*)d_out);
}

// Round 6
// 169.168 us; speedup vs baseline: 1.0176x; 1.0176x over previous
//
#include <hip/hip_runtime.h>

// ODE-RNN encoder: B=2048, T=64, HID=16, adaptive Tsit5 + GRU.
// Round 11: pure chain-stage deletions (R10 calibrated ~4-6 cy/stage; we are
// within ~10% of the dependent-latency floor; idle issue slots are free):
//  (a) tanh affine fold: layers 2/3 consume h=1-2r linearly -> w2'=-2*TS*w2,
//      w3'=-2*w3, seeds += rowsum(w); deletes fmaf(-2,rcp,1) from both tanh
//      layers of all 6 chained MLPs (12 stages/iter).
//  (b) tail: dinv = d*rcp(scale4) precomputed parallel to k7's MLP (kills the
//      err=d*se stage); fmax(1e-16) dropped (med3 clamps +-inf identically);
//      0.9 folded into exp2 arg via fmaf(-0.1, log2, log2(0.9)).
//  (c) stage-2 arg formed in gathered space: rotations of y',k1' computed in
//      the idle window after accept; G = pk_fma(d, s2_rot, y_rot) removes the
//      serial fma->gather chain behind d (the last-arriving value).
// rsum16 kept in the symmetric add form (fma-square would break bitwise
// lane-uniformity of accept across a sample's rows).
// Structure (R9): 32 lanes/sample, 2 samples/wave, 1024 blocks x 64; skewed
// state, col-split dot, permlane32_swap cross-half pair-sum, ROR4_HI re-skew.

#define T_STEPS 64
#define NB 2048
#define N_ODE_STEPS 16

typedef float v2f __attribute__((ext_vector_type(2)));
typedef int v2i __attribute__((ext_vector_type(2)));

__device__ __forceinline__ v2f make2(float a, float b) { v2f r; r.x = a; r.y = b; return r; }

// row_ror:r  => dst lane n gets src lane (n - r) & 15 (within 16-lane row)
#define ROR(x, r) __int_as_float(__builtin_amdgcn_update_dpp( \
    0, __float_as_int(x), 0x120 + (r), 0xF, 0xF, true))

// rotate-by-4 applied ONLY to rows 2,3 (lanes 32-63); rows 0,1 keep x.
#define ROR4_HI(x) __int_as_float(__builtin_amdgcn_update_dpp( \
    __float_as_int(x), __float_as_int(x), 0x124, 0xC, 0xF, false))

__device__ __forceinline__ float rsum16(float v) {
  v += ROR(v, 8);
  v += ROR(v, 4);
  v += ROR(v, 2);
  v += ROR(v, 1);
  return v;  // all 16 lanes hold the row sum (bitwise lane-uniform)
}

// cross-half combine: returns part + part_from(lane^32); bitwise symmetric.
__device__ __forceinline__ float xhalf_sum(float part) {
  v2i pr = __builtin_amdgcn_permlane32_swap(
      __float_as_int(part), __float_as_int(part), false, false);
  return __int_as_float(pr[0]) + __int_as_float(pr[1]);
}

struct G2 { v2f a, b; };

// rotations 0..3 of the (skewed) state within each 16-row: 3 DPP, depth 2
__device__ __forceinline__ G2 gather4(float x) {
  float r1 = ROR(x, 1);
  float r2 = ROR(x, 2);
  float r3 = ROR(r2, 1);
  G2 g; g.a = make2(x, r1); g.b = make2(r2, r3); return g;
}

// Full 16-col dot for row j (at every lane), then re-skewed to state layout.
__device__ __forceinline__ float dotG(const v2f (&WA)[2], const v2f (&WB)[2],
                                      const G2& g, float seed) {
  v2f aa = __builtin_elementwise_fma(g.a, WA[0], make2(seed, 0.0f));
  v2f bb = g.a * WB[0];
  aa = __builtin_elementwise_fma(g.b, WA[1], aa);
  bb = __builtin_elementwise_fma(g.b, WB[1], bb);
  float a  = aa.x + aa.y;          // A partial: row j, this lane's 4 cols
  float bs = bb.x + bb.y;          // B partial: row j+8, this lane's 4 cols
  float part = a + ROR(bs, 8);     // row j partial: 8 cols (this half)
  return ROR4_HI(xhalf_sum(part)); // all 16 cols, re-skewed
}

__device__ __forceinline__ float dotAB(const v2f (&WA)[2], const v2f (&WB)[2],
                                       float x, float seed) {
  G2 g = gather4(x);
  return dotG(WA, WB, g, seed);
}

// tanh residual: r = rcp(exp2(p)+1); tanh = 1 - 2r is folded into the
// CONSUMER's weights (w' = -2w, seed += rowsum(w)). p is pre-scaled.
__device__ __forceinline__ float tanh_res(float p) {
  return __builtin_amdgcn_rcpf(__builtin_amdgcn_exp2f(p) + 1.0f);
}

// sigmoid from a PRE-SCALED argument p = -log2(e)*x
__device__ __forceinline__ float sig_p(float p) {
  float e = __builtin_amdgcn_exp2f(p);
  return __builtin_amdgcn_rcpf(1.0f + e);
}

// unscaled tanh (n-gate: input is a runtime product; output used nonlinearly)
__device__ __forceinline__ float fast_tanh(float x) {
  float e = __builtin_amdgcn_exp2f(x * 2.885390081777927f);  // 2*log2(e)
  return fmaf(-2.0f, __builtin_amdgcn_rcpf(e + 1.0f), 1.0f);
}

// MLP from a pre-gathered layer-1 input.
__device__ __forceinline__ float mlp_fG(const G2& g0,
    const v2f (&w1a)[2], const v2f (&w1b)[2], float b1s,
    const v2f (&w2a)[2], const v2f (&w2b)[2], float b2s,
    const v2f (&w3a)[2], const v2f (&w3b)[2], float b3s) {
  float r1v = tanh_res(dotG(w1a, w1b, g0, b1s));      // w1,b1 scaled by TS
  float r2v = tanh_res(dotAB(w2a, w2b, r1v, b2s));    // w2' = -2*TS*w2
  return dotAB(w3a, w3b, r2v, b3s);                   // w3' = -2*w3 -> true k
}

__device__ __forceinline__ float mlp_f(float u,
    const v2f (&w1a)[2], const v2f (&w1b)[2], float b1s,
    const v2f (&w2a)[2], const v2f (&w2b)[2], float b2s,
    const v2f (&w3a)[2], const v2f (&w3b)[2], float b3s) {
  G2 g = gather4(u);
  return mlp_fG(g, w1a, w1b, b1s, w2a, w2b, b2s, w3a, w3b, b3s);
}

__global__
__attribute__((amdgpu_flat_work_group_size(64, 64), amdgpu_waves_per_eu(1, 1)))
void odern_kernel(
    const float* __restrict__ x_seq,
    const float* __restrict__ w1, const float* __restrict__ b1,
    const float* __restrict__ w2, const float* __restrict__ b2,
    const float* __restrict__ w3, const float* __restrict__ b3,
    const float* __restrict__ gru_wih, const float* __restrict__ gru_whh,
    const float* __restrict__ gru_b, const float* __restrict__ gru_bn,
    const float* __restrict__ pred_w, const float* __restrict__ pred_b,
    float* __restrict__ out) {
  const int tid = threadIdx.x;
  const int j = tid & 15;          // lane position within 16-row
  const int row16 = tid >> 4;      // 0..3
  const int smp = row16 & 1;       // sample-in-wave: rows {0,2}=0, {1,3}=1
  const int hf = row16 >> 1;       // half: 0 = cols j..j-7, 1 = cols j-4..j-15
  const int b = blockIdx.x * 2 + smp;
  const int jj = (j + 8) & 15;     // B-dot row
  const int base = (j - 4 * hf) & 15;  // hidden index of this lane's state slot

  const float TS = 2.885390081777927f;    // 2*log2(e)  (tanh input scale)
  const float SS = -1.4426950408889634f;  // -log2(e)   (sigmoid input scale)
  const float N2TS = -5.770780163555854f; // -2*TS

  // rowsums for the tanh affine fold (seeds, hf=0/row-j only)
  float rs2 = 0.0f, rs3 = 0.0f;
#pragma unroll
  for (int c = 0; c < 16; ++c) { rs2 += w2[j * 16 + c]; rs3 += w3[j * 16 + c]; }

  v2f w1a[2], w1b[2], w2a[2], w2b[2], w3a[2], w3b[2];
  v2f wha[2], whb[2], wza[2], wzb[2], wna[2], wnb[2];
#pragma unroll
  for (int p = 0; p < 2; ++p) {
    const int ca = (base - 2 * p) & 15;
    const int cb = (base - 2 * p - 1) & 15;
    w1a[p] = make2(w1[j * 16 + ca] * TS,  w1[j * 16 + cb] * TS);
    w1b[p] = make2(w1[jj * 16 + ca] * TS, w1[jj * 16 + cb] * TS);
    w2a[p] = make2(w2[j * 16 + ca] * N2TS,  w2[j * 16 + cb] * N2TS);
    w2b[p] = make2(w2[jj * 16 + ca] * N2TS, w2[jj * 16 + cb] * N2TS);
    w3a[p] = make2(w3[j * 16 + ca] * -2.0f,  w3[j * 16 + cb] * -2.0f);
    w3b[p] = make2(w3[jj * 16 + ca] * -2.0f, w3[jj * 16 + cb] * -2.0f);
    wha[p] = make2(gru_whh[j * 16 + ca] * SS,         gru_whh[j * 16 + cb] * SS);
    whb[p] = make2(gru_whh[jj * 16 + ca] * SS,        gru_whh[jj * 16 + cb] * SS);
    wza[p] = make2(gru_whh[(16 + j) * 16 + ca] * SS,  gru_whh[(16 + j) * 16 + cb] * SS);
    wzb[p] = make2(gru_whh[(16 + jj) * 16 + ca] * SS, gru_whh[(16 + jj) * 16 + cb] * SS);
    wna[p] = make2(gru_whh[(32 + j) * 16 + ca],  gru_whh[(32 + j) * 16 + cb]);
    wnb[p] = make2(gru_whh[(32 + jj) * 16 + ca], gru_whh[(32 + jj) * 16 + cb]);
  }
  // Seeds injected once per output row via the hf=0 A-chain.
  const float b1s = hf ? 0.0f : b1[j] * TS;
  const float b2s = hf ? 0.0f : (b2[j] + rs2) * TS;   // + rowsum(w2): h1=1-2r fold
  const float b3s = hf ? 0.0f : b3[j] + rs3;          // + rowsum(w3): h2=1-2r fold
  const float wih_r0 = hf ? 0.0f : gru_wih[j * 2] * SS;
  const float wih_r1 = hf ? 0.0f : gru_wih[j * 2 + 1] * SS;
  const float wih_z0 = hf ? 0.0f : gru_wih[(16 + j) * 2] * SS;
  const float wih_z1 = hf ? 0.0f : gru_wih[(16 + j) * 2 + 1] * SS;
  const float gb_r = hf ? 0.0f : gru_b[j] * SS;
  const float gb_z = hf ? 0.0f : gru_b[16 + j] * SS;
  const float bns  = hf ? 0.0f : gru_bn[j];
  const float wih_n0 = gru_wih[(32 + base) * 2];
  const float wih_n1 = gru_wih[(32 + base) * 2 + 1];
  const float gb_n = gru_b[32 + base];
  const float pwv = pred_w[base], pbv = pred_b[0];

  const float* xp = x_seq + (size_t)b * (T_STEPS * 2);

  float hst = 0.0f;
#pragma unroll 1
  for (int t = 0; t < T_STEPS; ++t) {
    const float x0 = xp[2 * t];
    const float x1 = xp[2 * t + 1];

    // ---- adaptive Tsit5 from t=0 to t=1, <=16 iterations, early exit ----
    float y = hst;
    float tt = 0.0f, dt = 1.0f;
    float k1 = mlp_f(y, w1a, w1b, b1s, w2a, w2b, b2s, w3a, w3b, b3s);
    // stage-2 gathered-arg state: rotations of y and s2 = 0.161*k1
    float yQ1 = ROR(y, 1), yQ2 = ROR(y, 2), yQ3 = ROR(yQ2, 1);
    float kQ1 = ROR(k1, 1), kQ2 = ROR(k1, 2), kQ3 = ROR(kQ2, 1);
    v2f ya = make2(y, yQ1), yb = make2(yQ2, yQ3);
    v2f s2a = make2(0.161f * k1, 0.161f * kQ1);
    v2f s2b = make2(0.161f * kQ2, 0.161f * kQ3);
#pragma unroll 1
    for (int s = 0; s < N_ODE_STEPS; ++s) {
      // Wave-uniform early exit (accept logic is row-uniform per sample).
      if (__all(tt >= 1.0f)) break;

      const float dt_c = fminf(dt, 1.0f - tt);
      const float d = dt_c;

      // stage 2: G formed directly in gathered space (rotation commutes
      // with elementwise fma): G = d*rot(s2) + rot(y), bitwise = gather(arg)
      v2f dd; dd.x = d; dd.y = d;
      G2 g2;
      g2.a = __builtin_elementwise_fma(dd, s2a, ya);
      g2.b = __builtin_elementwise_fma(dd, s2b, yb);
      float k2 = mlp_fG(g2, w1a, w1b, b1s, w2a, w2b, b2s, w3a, w3b, b3s);

      float s3 = fmaf(0.335480655492357f, k2, -0.008480655492356989f * k1);
      float k3 = mlp_f(fmaf(d, s3, y), w1a, w1b, b1s, w2a, w2b, b2s, w3a, w3b, b3s);

      float s4 = fmaf(4.3622954328695815f, k3,
                 fmaf(-6.359448489975075f, k2, 2.8971530571054935f * k1));
      float k4 = mlp_f(fmaf(d, s4, y), w1a, w1b, b1s, w2a, w2b, b2s, w3a, w3b, b3s);

      float s5 = fmaf(-0.09249506636175525f, k4,
                 fmaf(7.4955393428898365f, k3,
                 fmaf(-11.748883564062828f, k2, 5.325864828439257f * k1)));
      float k5 = mlp_f(fmaf(d, s5, y), w1a, w1b, b1s, w2a, w2b, b2s, w3a, w3b, b3s);

      float s6 = fmaf(-0.028269050394068383f, k5,
                 fmaf(-0.071584973281401f, k4,
                 fmaf(8.159367898576159f, k3,
                 fmaf(-12.92096931784711f, k2, 5.86145544294642f * k1))));
      float k6 = mlp_f(fmaf(d, s6, y), w1a, w1b, b1s, w2a, w2b, b2s, w3a, w3b, b3s);

      float sy = fmaf(2.324710524099774f, k6,
                 fmaf(-3.290069515436081f, k5,
                 fmaf(1.379008574103742f, k4,
                 fmaf(0.4798896504144996f, k3,
                 fmaf(0.01f, k2, 0.09646076681806523f * k1)))));
      float y_new = fmaf(d, sy, y);

      // error scale: ready in parallel with k7's MLP (only needs y, y_new)
      float scale4 = fmaf(0.04f, fmaxf(fabsf(y), fabsf(y_new)), 0.0004f);
      float dinv = d * __builtin_amdgcn_rcpf(scale4);

      float k7 = mlp_f(y_new, w1a, w1b, b1s, w2a, w2b, b2s, w3a, w3b, b3s);

      float se = fmaf(0.015151515151515152f, k7,
                 fmaf(-0.45808210592918697f, k6,
                 fmaf(0.5823571654525552f, k5,
                 fmaf(-0.1447110071732629f, k4,
                 fmaf(0.007880878010261995f, k3,
                 fmaf(-0.0008164344596567469f, k2, -0.001780011052225777f * k1))))));

      float r = se * dinv;              // err/scale with d folded in
      float err2 = rsum16(r * r);       // symmetric butterfly: lane-uniform
      // no fmax(1e-16): med3 clamps the +-inf / huge-fac cases identically

      const bool acc = err2 <= 1.0f;
      y = acc ? y_new : y;
      tt = acc ? tt + dt_c : tt;
      k1 = acc ? k7 : k1;   // FSAL

      // fac = 0.9*err2^-0.1, 0.9 folded: exp2(fma(-0.1, log2(err2), log2 0.9))
      float fac = __builtin_amdgcn_exp2f(
          fmaf(-0.1f, __builtin_amdgcn_logf(err2), -0.15200309344504997f));
      fac = __builtin_amdgcn_fmed3f(fac, 0.2f, 10.0f);
      dt = dt_c * fac;

      // next-iter stage-2 rotations (idle window; off the critical path)
      float yR1 = ROR(y, 1), yR2 = ROR(y, 2), yR3 = ROR(yR2, 1);
      float kR1 = ROR(k1, 1), kR2 = ROR(k1, 2), kR3 = ROR(kR2, 1);
      ya = make2(y, yR1); yb = make2(yR2, yR3);
      s2a = make2(0.161f * k1, 0.161f * kR1);
      s2b = make2(0.161f * kR2, 0.161f * kR3);
    }

    // ---- GRU update: one shared gather feeds all 3 dots ----
    float ir  = fmaf(wih_r1, x1, fmaf(wih_r0, x0, gb_r));   // pre-scaled, 0 at hf=1
    float iz  = fmaf(wih_z1, x1, fmaf(wih_z0, x0, gb_z));   // pre-scaled, 0 at hf=1
    float in_ = fmaf(wih_n1, x1, fmaf(wih_n0, x0, gb_n));   // skewed, all lanes
    G2 gy = gather4(y);
    float pre_r = dotG(wha, whb, gy, ir);    // -log2e*(ir + hr)   (skewed)
    float pre_z = dotG(wza, wzb, gy, iz);    // -log2e*(iz + hz)   (skewed)
    float hnb   = dotG(wna, wnb, gy, bns);   // hn + bn            (skewed)
    float rg = sig_p(pre_r);
    float zg = sig_p(pre_z);
    float ng = fast_tanh(fmaf(rg, hnb, in_));
    hst = fmaf(zg, y - ng, ng);
  }

  // ---- final projection: out[b] = h . pred_w + pred_b ----
  float ps = rsum16(hst * pwv);
  if (hf == 0 && j == 0) out[b] = ps + pbv;   // rows 0,1: one writer per sample
}

extern "C" void kernel_launch(void* const* d_in, const int* in_sizes, int n_in,
                              void* d_out, int out_size, void* d_ws, size_t ws_size,
                              hipStream_t stream) {
  (void)in_sizes; (void)n_in; (void)out_size; (void)d_ws; (void)ws_size;
  odern_kernel<<<dim3(NB / 2), dim3(64), 0, stream>>>(
      (const float*)d_in[0],
      (const float*)d_in[1], (const float*)d_in[2],
      (const float*)d_in[3], (const float*)d_in[4],
      (const float*)d_in[5], (const float*)d_in[6],
      (const float*)d_in[7], (const float*)d_in[8],
      (const float*)d_in[9], (const float*)d_in[10],
      (const float*)d_in[11], (const float*)d_in[12],
      (float*)d_out);
}